// Round 14
// baseline (424.922 us; speedup 1.0000x reference)
//
#include <hip/hip_runtime.h>

// Problem constants (fixed by setup_inputs)
#define BG    4        // num_graphs
#define TT    12       // timesteps
#define NN    10000    // nodes per graph
#define EN    200000   // membership entries
#define NSEG  40000    // n*B segments
#define NROWS 40000    // B*n output rows
#define MPAD  40000    // legacy (Cff rows)
#define MP2   40192    // 157*256 padded M for 256-row tiles
#define RT    157      // row tiles (MP2/256)
#define KD    832      // padded in_dim (780 -> 832) ; also h* row stride
#define KA0   160      // padded K for layer0 GEMM: 12 features + 128 Cf + 20 zero
#define NPW   896      // padded N for weight tiles (7*128)
#define NT    7        // N-tiles per row panel (NPW/128)
#define KW3   896      // Wt3 row stride (padded so fused tiles never OOB)

typedef __attribute__((ext_vector_type(8))) short bf8_t;   // 8 bf16 (4 VGPR) MFMA A/B frag
typedef __attribute__((ext_vector_type(4))) float f4_t;    // 4 f32 MFMA C/D frag

__device__ __forceinline__ unsigned short f2bf(float x) {  // RNE f32->bf16
  unsigned int u = __float_as_uint(x);
  u += 0x7fffu + ((u >> 16) & 1u);
  return (unsigned short)(u >> 16);
}

#define GLDS16(src, dst) __builtin_amdgcn_global_load_lds( \
    (const __attribute__((address_space(1))) void*)(src),  \
    (__attribute__((address_space(3))) void*)(dst), 16, 0, 0)

#define LKW0  asm volatile("s_waitcnt lgkmcnt(0)" ::: "memory")
#define VMW0  asm volatile("s_waitcnt vmcnt(0)" ::: "memory")
#define VMW6  asm volatile("s_waitcnt vmcnt(6)" ::: "memory")
#define VMW12 asm volatile("s_waitcnt vmcnt(12)" ::: "memory")
#define SBAR0 __builtin_amdgcn_sched_barrier(0)

// ---------------- prep ----------------
__global__ void k_outinit(float* __restrict__ out3, const float* __restrict__ b3) {
  int i = blockIdx.x * 256 + threadIdx.x;
  if (i < NROWS * 12) out3[i] = b3[i % 12];
}

__global__ void k_count(const int* __restrict__ mapper, int* __restrict__ counts) {
  int e = blockIdx.x * 256 + threadIdx.x;
  if (e < EN) atomicAdd(&counts[mapper[e]], 1);
}

// Cf scatter: entry e contributes 1 to Cff[r][batch[e]], r = output row of segment mapper[e]
__global__ void k_scatterCf(const int* __restrict__ mapper, const int* __restrict__ batch,
                            float* __restrict__ Cff) {
  int e = blockIdx.x * 256 + threadIdx.x;
  if (e < EN) {
    const int s = mapper[e];
    const int r = (s % BG) * NN + s / BG;   // inverse of s = (r%NN)*BG + r/NN
    atomicAdd(&Cff[(size_t)r * 128 + batch[e]], 1.0f);
  }
}

// A = [features(12) | Cf(128) | 0(20)] as bf16, [MP2][KA0]
__global__ void k_buildA(const float* __restrict__ features, const int* __restrict__ counts,
                         const float* __restrict__ Cff, unsigned short* __restrict__ A) {
  int idx = blockIdx.x * 256 + threadIdx.x;
  if (idx >= MP2 * KA0) return;
  const int r = idx / KA0, c = idx - r * KA0;
  float v = 0.f;
  if (r < NROWS) {
    if (c < 12) {
      v = features[(size_t)r * TT + c];
    } else if (c < 140) {
      const int s = (r % NN) * BG + (r / NN);
      const int cnt = counts[s];
      const float inv = 1.f / (float)(cnt > 0 ? cnt : 1);
      v = Cff[(size_t)r * 128 + (c - 12)] * inv;
    }
  }
  A[idx] = f2bf(v);
}

// One kernel for all weight/bias prep (ranges: Wt1, Wt2, Wt3, biases, WTB)
__global__ void k_prep(const float* __restrict__ W0, const float* __restrict__ fW0,
                       const float* __restrict__ W1, const float* __restrict__ W2,
                       const float* __restrict__ W3,
                       const float* __restrict__ b0, const float* __restrict__ b1,
                       const float* __restrict__ b2,
                       unsigned short* __restrict__ Wt1, unsigned short* __restrict__ Wt2,
                       unsigned short* __restrict__ Wt3,
                       float* __restrict__ bp0, float* __restrict__ bp1,
                       float* __restrict__ bp2, unsigned short* __restrict__ WTB) {
  constexpr int S1 = NPW * KD;
  constexpr int S3 = 16 * KW3;
  constexpr int SB = 3 * NPW;
  constexpr int S5 = NPW * KA0;
  int idx = blockIdx.x * 256 + threadIdx.x;
  if (idx < 2 * S1) {
    const int which = idx / S1, rem = idx - which * S1;
    const int n = rem / KD, k = rem - n * KD;
    const float* W = which ? W2 : W1;
    float v = (n < 780 && k < 780) ? W[(size_t)k * 780 + n] : 0.f;
    (which ? Wt2 : Wt1)[rem] = f2bf(v);
    return;
  }
  idx -= 2 * S1;
  if (idx < S3) {
    const int n = idx / KW3, k = idx - n * KW3;
    float v = (n < 12 && k < 780) ? W3[(size_t)k * 12 + n] : 0.f;
    Wt3[idx] = f2bf(v);
    return;
  }
  idx -= S3;
  if (idx < SB) {
    const int which = idx / NPW, c = idx - which * NPW;
    const float* src = which == 0 ? b0 : (which == 1 ? b1 : b2);
    float* dst = which == 0 ? bp0 : (which == 1 ? bp1 : bp2);
    dst[c] = (c < 780) ? src[c] : 0.f;
    return;
  }
  idx -= SB;
  if (idx < S5) {
    const int n = idx / KA0, k = idx - n * KA0;
    float v = 0.f;
    if (n < 780) {
      if (k < 12) v = W0[(size_t)k * 780 + n];
      else if (k < 140) v = fW0[(size_t)(k - 12) * KD + n];
    }
    WTB[idx] = f2bf(v);
  }
}

// flatW0[j][c] = sum_k flat[j][k] * W0[12+k][c], j<128, c<780 (0 for 780<=c<832)
// flat[j][t*64+f] = mixer_x[j%4][t][j/4][f]
__global__ __launch_bounds__(256) void k_flatW0(const float* __restrict__ mixer,
                                                const float* __restrict__ W0,
                                                float* __restrict__ fW0) {
  __shared__ float sA[8][768];       // 24 KB: 8 A-rows
  __shared__ float sRed[4][64][9];   // 9.2 KB, pad 9 -> conflict-free
  const int tid = threadIdx.x;
  const int c0 = blockIdx.x * 64, j0 = blockIdx.y * 8;
  for (int i = tid; i < 8 * 768; i += 256) {
    int jj = i / 768;
    int k = i - jj * 768;
    int j = j0 + jj;
    int tt = k >> 6, ff = k & 63;
    sA[jj][k] = mixer[(((j & 3) * TT + tt) * 32 + (j >> 2)) * 64 + ff];
  }
  __syncthreads();
  const int cc = tid & 63, ks = tid >> 6;
  const int c = c0 + cc;
  float acc[8] = {};
  if (c < 780) {
    const float* wp = W0 + (size_t)(12 + ks * 192) * 780 + c;
    #pragma unroll 4
    for (int k = ks * 192; k < ks * 192 + 192; ++k) {
      const float w = *wp; wp += 780;
      #pragma unroll
      for (int jj = 0; jj < 8; ++jj) acc[jj] = fmaf(sA[jj][k], w, acc[jj]);
    }
  }
  #pragma unroll
  for (int jj = 0; jj < 8; ++jj) sRed[ks][cc][jj] = acc[jj];
  __syncthreads();
  for (int o = tid; o < 512; o += 256) {
    const int oc = o & 63, jj = o >> 6;
    const int wc = c0 + oc;
    if (wc < KD) {
      float s = sRed[0][oc][jj] + sRed[1][oc][jj] + sRed[2][oc][jj] + sRed[3][oc][jj];
      fW0[(size_t)(j0 + jj) * KD + wc] = s;  // cols >=780 stayed 0
    }
  }
}

// ---------------- dense layers: C = relu(A @ W + b), bf16 MFMA ----------------
// R14: 256x128 block tile (wave output 128x64, acc[8][4]) — raises LDS
// arithmetic intensity 1.33x (12 frag-reads per 32 MFMA vs 8 per 16):
// per-block K-slab LDS ~576cyc < MFMA ~620cyc -> MFMA-bound at last.
// M pads to 40192 (+0.3%) instead of growing N (+14%).
// Pipeline = verified R13 3-deep counted structure (6 loads/stage ->
// vmcnt 12/6/0). Swizzle class g(r)=(r>>1)&3 (not r&3): spreads 16 rows
// over all 8 four-bank groups -> 2-way (free) instead of 4-way.
template<int KA, bool FUSE>
__global__ __launch_bounds__(256) void gemm_relu(
    const unsigned short* __restrict__ A, const unsigned short* __restrict__ WT,
    const float* __restrict__ bias, unsigned short* __restrict__ C,
    const unsigned short* __restrict__ W3t, float* __restrict__ out3) {
  constexpr int BK   = 32;
  constexpr int NKT  = KA / BK;
  constexpr int ABUF = 256 * BK * 2;           // 16KB A per buffer
  constexpr int BBUF = 128 * BK * 2;           // 8KB  B per buffer
  __shared__ char smem[3 * (ABUF + BBUF)];     // 72KB
  const int tid = threadIdx.x, lane = tid & 63, wid = tid >> 6;
  const int wm = wid >> 1, wn = wid & 1;

  // bijective XCD swizzle (nwg = RT*NT = 1099)
  const int nwg = gridDim.x;
  const int q = nwg >> 3, r8 = nwg & 7;
  const int xcd = blockIdx.x & 7, bidx = blockIdx.x >> 3;
  const int linear = (xcd < r8 ? xcd * (q + 1) : r8 * (q + 1) + (xcd - r8) * q) + bidx;
  const int rowtile = linear / NT, ntile = linear - rowtile * NT;

  const int row0 = rowtile * 256, n0 = ntile * 128;
  const char* gA = (const char*)A + (size_t)row0 * (KA * 2);
  const char* gB = (const char*)WT + (size_t)n0 * (KA * 2);
  const int frow = lane & 15;

  // t-invariant swizzled frag offsets (byte units within a buffer)
  int offA[8], offB[4];
  {
    const int c16r = lane >> 4;                 // 0..3
    #pragma unroll
    for (int i = 0; i < 8; ++i) {
      const int ra = wm * 128 + i * 16 + frow;
      offA[i] = ra * (BK * 2) + ((c16r ^ ((ra >> 1) & 3)) * 16);
    }
    #pragma unroll
    for (int i = 0; i < 4; ++i) {
      const int rb = wn * 64 + i * 16 + frow;
      offB[i] = rb * (BK * 2) + ((c16r ^ ((rb >> 1) & 3)) * 16);
    }
  }

  auto bufA = [&](int b) { return smem + b * (ABUF + BBUF); };
  auto bufB = [&](int b) { return smem + b * (ABUF + BBUF) + ABUF; };

  auto stage = [&](int b, int kt) {
    const int kb = kt * (BK * 2);
    #pragma unroll
    for (int L = 0; L < 4; ++L) {               // A: 1024 segs (256 rows x 4)
      const int seg = L * 256 + tid;
      const int row = seg >> 2, c16 = seg & 3;
      const int c16s = c16 ^ ((row >> 1) & 3);  // pre-swizzled source
      GLDS16(gA + (size_t)row * (KA * 2) + kb + c16s * 16, bufA(b) + seg * 16);
    }
    #pragma unroll
    for (int L = 0; L < 2; ++L) {               // B: 512 segs (128 rows x 4)
      const int seg = L * 256 + tid;
      const int row = seg >> 2, c16 = seg & 3;
      const int c16s = c16 ^ ((row >> 1) & 3);
      GLDS16(gB + (size_t)row * (KA * 2) + kb + c16s * 16, bufB(b) + seg * 16);
    }
  };

  f4_t acc[8][4] = {};

  // prologue: tiles 0,1,2 in flight (18 loads); wait tile 0
  stage(0, 0);
  stage(1, 1);
  stage(2, 2);
  VMW12;
  __builtin_amdgcn_s_barrier();

  #pragma unroll
  for (int t = 0; t < NKT; ++t) {
    const int cur = t % 3;
    bf8_t af[8], bfv[4];
    #pragma unroll
    for (int i = 0; i < 8; ++i) af[i]  = *(const bf8_t*)(bufA(cur) + offA[i]);
    #pragma unroll
    for (int i = 0; i < 4; ++i) bfv[i] = *(const bf8_t*)(bufB(cur) + offB[i]);
    if (t < NKT - 1) {
      LKW0;                               // own frag reads done (regs hold tile t)
      __builtin_amdgcn_s_barrier();       // all waves done reading buf[cur]
      SBAR0;                              // pin: no motion across the fence
      if (t + 3 < NKT) stage(cur, t + 3); // overwrite freed buf; stays in flight
    } else {
      LKW0;
      SBAR0;
    }
    __builtin_amdgcn_s_setprio(1);
    #pragma unroll
    for (int mi = 0; mi < 8; ++mi)
      #pragma unroll
      for (int ni = 0; ni < 4; ++ni)
        acc[mi][ni] = __builtin_amdgcn_mfma_f32_16x16x32_bf16(bfv[ni], af[mi], acc[mi][ni], 0, 0, 0);
    __builtin_amdgcn_s_setprio(0);
    if (t < NKT - 1) {
      if (t + 3 < NKT)      { VMW12; }    // tiles t+2,t+3 stay in flight
      else if (t + 2 < NKT) { VMW6;  }    // only t+2 in flight
      else                  { VMW0;  }    // last prefetch: full drain
      __builtin_amdgcn_s_barrier();
    }
  }

  const int cq = (lane >> 4) * 4;
  if constexpr (!FUSE) {
    #pragma unroll
    for (int mi = 0; mi < 8; ++mi) {
      const int r = row0 + wm * 128 + mi * 16 + frow;
      unsigned short* crow = C + (size_t)r * KD;
      #pragma unroll
      for (int ni = 0; ni < 4; ++ni) {
        const int c = n0 + wn * 64 + ni * 16 + cq;
        if (c < KD) {  // wave-uniform per fragment
          f4_t v = acc[mi][ni];
          const f4_t bb = *(const f4_t*)(bias + c);
          float v0 = fmaxf(v[0] + bb[0], 0.f);
          float v1 = fmaxf(v[1] + bb[1], 0.f);
          float v2 = fmaxf(v[2] + bb[2], 0.f);
          float v3 = fmaxf(v[3] + bb[3], 0.f);
          uint2 pk;
          pk.x = (unsigned int)f2bf(v0) | ((unsigned int)f2bf(v1) << 16);
          pk.y = (unsigned int)f2bf(v2) | ((unsigned int)f2bf(v3) << 16);
          *(uint2*)(crow + c) = pk;
        }
      }
    }
  } else {
    // ---- fused layer-3 epilogue ----
    // relu tile -> LDS [256][128] bf16 (64KB within smem), byte ^= (lr&7)<<4.
    unsigned short* sT = (unsigned short*)smem;
    __syncthreads();   // all waves past their last frag reads before overwrite
    #pragma unroll
    for (int mi = 0; mi < 8; ++mi) {
      const int lr = wm * 128 + mi * 16 + frow;
      #pragma unroll
      for (int ni = 0; ni < 4; ++ni) {
        const int lc = wn * 64 + ni * 16 + cq;
        f4_t v = acc[mi][ni];
        const f4_t bb = *(const f4_t*)(bias + (n0 + lc));   // bias is NPW-wide
        float v0 = fmaxf(v[0] + bb[0], 0.f);
        float v1 = fmaxf(v[1] + bb[1], 0.f);
        float v2 = fmaxf(v[2] + bb[2], 0.f);
        float v3 = fmaxf(v[3] + bb[3], 0.f);
        uint2 pk;
        pk.x = (unsigned int)f2bf(v0) | ((unsigned int)f2bf(v1) << 16);
        pk.y = (unsigned int)f2bf(v2) | ((unsigned int)f2bf(v3) << 16);
        const int bo = (lr * 256 + lc * 2) ^ ((lr & 7) << 4);
        *(uint2*)((char*)sT + bo) = pk;
      }
    }
    __syncthreads();
    // mini-GEMM: out_partial[256][16] = tile[256][128] @ Wt3[n0:n0+128]^T
    const int fk = (lane >> 4) * 8;
    f4_t acc2[4] = {};
    #pragma unroll
    for (int kk2 = 0; kk2 < 4; ++kk2) {
      const bf8_t bw = *(const bf8_t*)(W3t + (size_t)frow * KW3 + n0 + kk2 * 32 + fk);
      #pragma unroll
      for (int mi2 = 0; mi2 < 4; ++mi2) {
        const int lr2 = wid * 64 + mi2 * 16 + frow;
        const int bo = (lr2 * 256 + (kk2 * 32 + fk) * 2) ^ ((lr2 & 7) << 4);
        const bf8_t av = *(const bf8_t*)((char*)sT + bo);
        acc2[mi2] = __builtin_amdgcn_mfma_f32_16x16x32_bf16(bw, av, acc2[mi2], 0, 0, 0);
      }
    }
    // atomic accumulate into out (pre-initialized to b3)
    #pragma unroll
    for (int mi2 = 0; mi2 < 4; ++mi2) {
      const int r2 = row0 + wid * 64 + mi2 * 16 + frow;
      if (r2 < NROWS && cq < 12) {
        float* orow = out3 + (size_t)r2 * 12 + cq;
        atomicAdd(&orow[0], acc2[mi2][0]);
        atomicAdd(&orow[1], acc2[mi2][1]);
        atomicAdd(&orow[2], acc2[mi2][2]);
        atomicAdd(&orow[3], acc2[mi2][3]);
      }
    }
  }
}

// ---------------- host ----------------
extern "C" void kernel_launch(void* const* d_in, const int* in_sizes, int n_in,
                              void* d_out, int out_size, void* d_ws, size_t ws_size,
                              hipStream_t stream) {
  const float* mixer    = (const float*)d_in[0];
  const float* features = (const float*)d_in[1];
  const int*   sg_batch = (const int*)d_in[2];
  const int*   sg_map   = (const int*)d_in[3];
  const float* W0 = (const float*)d_in[4];  const float* b0 = (const float*)d_in[5];
  const float* W1 = (const float*)d_in[6];  const float* b1 = (const float*)d_in[7];
  const float* W2 = (const float*)d_in[8];  const float* b2 = (const float*)d_in[9];
  const float* W3 = (const float*)d_in[10]; const float* b3 = (const float*)d_in[11];
  float* out = (float*)d_out;

  char* wsp = (char*)d_ws;
  auto alloc = [&](size_t bytes) { char* p = wsp; wsp += (bytes + 255) & ~(size_t)255; return p; };
  unsigned short* h0  = (unsigned short*)alloc((size_t)MP2 * KD * 2);   // 66.9 MB
  unsigned short* h1  = (unsigned short*)alloc((size_t)MP2 * KD * 2);   // 66.9 MB
  unsigned short* Wt1 = (unsigned short*)alloc((size_t)NPW * KD * 2);
  unsigned short* Wt2 = (unsigned short*)alloc((size_t)NPW * KD * 2);
  unsigned short* Wt3 = (unsigned short*)alloc((size_t)16 * KW3 * 2);
  unsigned short* WTB = (unsigned short*)alloc((size_t)NPW * KA0 * 2);
  float* bp0   = (float*)alloc(NPW * 4);
  float* bp1   = (float*)alloc(NPW * 4);
  float* bp2   = (float*)alloc(NPW * 4);
  float* fW0   = (float*)alloc((size_t)128 * KD * 4);
  int* counts  = (int*)alloc(NSEG * 4);
  // Cff (20.5 MB f32) and Abuf (12.9 MB bf16) alias h1's space: both are dead
  // before the first write to h1 (layer-1 GEMM output).
  float* Cff = (float*)h1;
  unsigned short* Abuf = (unsigned short*)((char*)h1 + (((size_t)MPAD * 128 * 4 + 255) & ~(size_t)255));

  // init: counts=0, Cff=0 (memset), out=b3 (small kernel)
  hipMemsetAsync(counts, 0, NSEG * 4, stream);
  hipMemsetAsync(Cff, 0, (size_t)MPAD * 128 * 4, stream);
  k_outinit<<<(NROWS * 12 + 255) / 256, 256, 0, stream>>>(out, b3);

  k_count<<<(EN + 255) / 256, 256, 0, stream>>>(sg_map, counts);
  k_scatterCf<<<(EN + 255) / 256, 256, 0, stream>>>(sg_map, sg_batch, Cff);

  // weight prep
  k_flatW0<<<dim3(13, 16), 256, 0, stream>>>(mixer, W0, fW0);
  {
    const int total = 2 * (NPW * KD) + 16 * KW3 + 3 * NPW + NPW * KA0;
    k_prep<<<(total + 255) / 256, 256, 0, stream>>>(W0, fW0, W1, W2, W3, b0, b1, b2,
                                                    Wt1, Wt2, Wt3, bp0, bp1, bp2, WTB);
  }

  // layer-0 operand A = [features | Cf | 0]
  k_buildA<<<(MP2 * KA0 + 255) / 256, 256, 0, stream>>>(features, counts, Cff, Abuf);

  // layer 0 as GEMM (K=160) -> h0
  gemm_relu<KA0, false><<<RT * NT, 256, 0, stream>>>(Abuf, WTB, bp0, h0, nullptr, nullptr);

  // layer 1 (K=832) -> h1
  gemm_relu<KD, false><<<RT * NT, 256, 0, stream>>>(h0, Wt1, bp1, h1, nullptr, nullptr);

  // layer 2 + fused layer 3 (K=832): atomic out += tile @ Wt3
  gemm_relu<KD, true><<<RT * NT, 256, 0, stream>>>(h1, Wt2, bp2, nullptr, Wt3, out);
}

// Round 15
// 342.689 us; speedup vs baseline: 1.2400x; 1.2400x over previous
//
#include <hip/hip_runtime.h>

// Problem constants (fixed by setup_inputs)
#define BG    4        // num_graphs
#define TT    12       // timesteps
#define NN    10000    // nodes per graph
#define EN    200000   // membership entries
#define NSEG  40000    // n*B segments
#define NROWS 40000    // B*n output rows
#define MPAD  40064    // 313*128
#define KD    832      // padded in_dim (780 -> 832) ; also h* row stride
#define KA0   160      // padded K for layer0 GEMM: 12 features + 128 Cf + 20 zero
#define NPW   896      // padded N for weight tiles (7*128)
#define NT    7        // N-tiles per row panel (NPW/128)
#define KW3   896      // Wt3 row stride (padded so fused tiles never OOB)

typedef __attribute__((ext_vector_type(8))) short bf8_t;   // 8 bf16 (4 VGPR) MFMA A/B frag
typedef __attribute__((ext_vector_type(4))) float f4_t;    // 4 f32 MFMA C/D frag

__device__ __forceinline__ unsigned short f2bf(float x) {  // RNE f32->bf16
  unsigned int u = __float_as_uint(x);
  u += 0x7fffu + ((u >> 16) & 1u);
  return (unsigned short)(u >> 16);
}

#define GLDS16(src, dst) __builtin_amdgcn_global_load_lds( \
    (const __attribute__((address_space(1))) void*)(src),  \
    (__attribute__((address_space(3))) void*)(dst), 16, 0, 0)

#define LKW0 asm volatile("s_waitcnt lgkmcnt(0)" ::: "memory")
#define VMW0 asm volatile("s_waitcnt vmcnt(0)" ::: "memory")
#define VMW4 asm volatile("s_waitcnt vmcnt(4)" ::: "memory")
#define VMW8 asm volatile("s_waitcnt vmcnt(8)" ::: "memory")
#define SBAR0 __builtin_amdgcn_sched_barrier(0)

// ---------------- prep ----------------
__global__ void k_outinit(float* __restrict__ out3, const float* __restrict__ b3) {
  int i = blockIdx.x * 256 + threadIdx.x;
  if (i < NROWS * 12) out3[i] = b3[i % 12];
}

// R15: fused count + Cf scatter (one pass over E)
__global__ void k_edges(const int* __restrict__ mapper, const int* __restrict__ batch,
                        int* __restrict__ counts, float* __restrict__ Cff) {
  int e = blockIdx.x * 256 + threadIdx.x;
  if (e < EN) {
    const int s = mapper[e];
    atomicAdd(&counts[s], 1);
    const int r = (s % BG) * NN + s / BG;   // inverse of s = (r%NN)*BG + r/NN
    atomicAdd(&Cff[(size_t)r * 128 + batch[e]], 1.0f);
  }
}

// A = [features(12) | Cf(128) | 0(20)] as bf16, [MPAD][KA0]
__global__ void k_buildA(const float* __restrict__ features, const int* __restrict__ counts,
                         const float* __restrict__ Cff, unsigned short* __restrict__ A) {
  int idx = blockIdx.x * 256 + threadIdx.x;
  if (idx >= MPAD * KA0) return;
  const int r = idx / KA0, c = idx - r * KA0;
  float v = 0.f;
  if (r < NROWS) {
    if (c < 12) {
      v = features[(size_t)r * TT + c];
    } else if (c < 140) {
      const int s = (r % NN) * BG + (r / NN);
      const int cnt = counts[s];
      const float inv = 1.f / (float)(cnt > 0 ? cnt : 1);
      v = Cff[(size_t)r * 128 + (c - 12)] * inv;
    }
  }
  A[idx] = f2bf(v);
}

// One kernel for all weight/bias prep. R15: COALESCED reads — lanes walk n
// (contiguous W row), transposed writes merge in L2 (Wt* are L2-resident).
__global__ void k_prep(const float* __restrict__ W0, const float* __restrict__ fW0,
                       const float* __restrict__ W1, const float* __restrict__ W2,
                       const float* __restrict__ W3,
                       const float* __restrict__ b0, const float* __restrict__ b1,
                       const float* __restrict__ b2,
                       unsigned short* __restrict__ Wt1, unsigned short* __restrict__ Wt2,
                       unsigned short* __restrict__ Wt3,
                       float* __restrict__ bp0, float* __restrict__ bp1,
                       float* __restrict__ bp2, unsigned short* __restrict__ WTB) {
  constexpr int S1 = NPW * KD;
  constexpr int S3 = 16 * KW3;
  constexpr int SB = 3 * NPW;
  constexpr int S5 = NPW * KA0;
  int idx = blockIdx.x * 256 + threadIdx.x;
  if (idx < 2 * S1) {
    const int which = idx / S1, rem = idx - which * S1;
    const int k = rem / NPW, n = rem - k * NPW;     // consecutive n -> coalesced read
    const float* W = which ? W2 : W1;
    float v = (n < 780 && k < 780) ? W[(size_t)k * 780 + n] : 0.f;
    (which ? Wt2 : Wt1)[(size_t)n * KD + k] = f2bf(v);
    return;
  }
  idx -= 2 * S1;
  if (idx < S3) {
    const int n = idx / KW3, k = idx - n * KW3;     // tiny (14K), leave as-is
    float v = (n < 12 && k < 780) ? W3[(size_t)k * 12 + n] : 0.f;
    Wt3[idx] = f2bf(v);
    return;
  }
  idx -= S3;
  if (idx < SB) {
    const int which = idx / NPW, c = idx - which * NPW;
    const float* src = which == 0 ? b0 : (which == 1 ? b1 : b2);
    float* dst = which == 0 ? bp0 : (which == 1 ? bp1 : bp2);
    dst[c] = (c < 780) ? src[c] : 0.f;
    return;
  }
  idx -= SB;
  if (idx < S5) {
    const int k = idx / NPW, n = idx - k * NPW;     // coalesced read
    float v = 0.f;
    if (n < 780) {
      if (k < 12) v = W0[(size_t)k * 780 + n];
      else if (k < 140) v = fW0[(size_t)(k - 12) * KD + n];
    }
    WTB[(size_t)n * KA0 + k] = f2bf(v);
  }
}

// flatW0[j][c] = sum_k flat[j][k] * W0[12+k][c], j<128, c<780 (0 for 780<=c<832)
// flat[j][t*64+f] = mixer_x[j%4][t][j/4][f]
__global__ __launch_bounds__(256) void k_flatW0(const float* __restrict__ mixer,
                                                const float* __restrict__ W0,
                                                float* __restrict__ fW0) {
  __shared__ float sA[8][768];       // 24 KB: 8 A-rows
  __shared__ float sRed[4][64][9];   // 9.2 KB, pad 9 -> conflict-free
  const int tid = threadIdx.x;
  const int c0 = blockIdx.x * 64, j0 = blockIdx.y * 8;
  for (int i = tid; i < 8 * 768; i += 256) {
    int jj = i / 768;
    int k = i - jj * 768;
    int j = j0 + jj;
    int tt = k >> 6, ff = k & 63;
    sA[jj][k] = mixer[(((j & 3) * TT + tt) * 32 + (j >> 2)) * 64 + ff];
  }
  __syncthreads();
  const int cc = tid & 63, ks = tid >> 6;
  const int c = c0 + cc;
  float acc[8] = {};
  if (c < 780) {
    const float* wp = W0 + (size_t)(12 + ks * 192) * 780 + c;
    #pragma unroll 4
    for (int k = ks * 192; k < ks * 192 + 192; ++k) {
      const float w = *wp; wp += 780;
      #pragma unroll
      for (int jj = 0; jj < 8; ++jj) acc[jj] = fmaf(sA[jj][k], w, acc[jj]);
    }
  }
  #pragma unroll
  for (int jj = 0; jj < 8; ++jj) sRed[ks][cc][jj] = acc[jj];
  __syncthreads();
  for (int o = tid; o < 512; o += 256) {
    const int oc = o & 63, jj = o >> 6;
    const int wc = c0 + oc;
    if (wc < KD) {
      float s = sRed[0][oc][jj] + sRed[1][oc][jj] + sRed[2][oc][jj] + sRed[3][oc][jj];
      fW0[(size_t)(j0 + jj) * KD + wc] = s;  // cols >=780 stayed 0
    }
  }
}

// ---------------- dense layers: C = relu(A @ W + b), bf16 MFMA ----------------
// R15 = R13 structure reverted (measured best: 342 us total): 128x128 tile,
// BK=32, 3-deep counted pipeline, 48KB LDS -> 3 blocks/CU. Only change:
// swizzle class g(r) = (r>>1)&3 (R14-verified, conflicts 8.1M -> 0.8M).
// R14's 256x128 tile REVERTED (occupancy collapse 28%->9%, 90->120us).
template<int KA, bool FUSE>
__global__ __launch_bounds__(256) void gemm_relu(
    const unsigned short* __restrict__ A, const unsigned short* __restrict__ WT,
    const float* __restrict__ bias, unsigned short* __restrict__ C,
    const unsigned short* __restrict__ W3t, float* __restrict__ out3) {
  constexpr int BK   = 32;
  constexpr int SEGR = BK / 8;                 // 4 x 16B chunks per row
  constexpr int MASK = SEGR - 1;
  constexpr int NISS = (128 * SEGR) / 256;     // 2 per-thread issues per operand
  constexpr int NKT  = KA / BK;
  constexpr int BUFB = 128 * BK * 2;           // 8KB per operand per buffer
  __shared__ char smem[3 * 2 * BUFB];          // 48KB: 3 x (sA 8K + sB 8K)
  const int tid = threadIdx.x, lane = tid & 63, wid = tid >> 6;
  const int wm = wid >> 1, wn = wid & 1;

  // bijective XCD swizzle (nwg = 313*NT = 2191)
  const int nwg = gridDim.x;
  const int q = nwg >> 3, r8 = nwg & 7;
  const int xcd = blockIdx.x & 7, bidx = blockIdx.x >> 3;
  const int linear = (xcd < r8 ? xcd * (q + 1) : r8 * (q + 1) + (xcd - r8) * q) + bidx;
  const int rowtile = linear / NT, ntile = linear - rowtile * NT;

  const int row0 = rowtile * 128, n0 = ntile * 128;
  const char* gA = (const char*)A + (size_t)row0 * (KA * 2);
  const char* gB = (const char*)WT + (size_t)n0 * (KA * 2);
  const int frow = lane & 15;

  // t-invariant swizzled frag offsets (byte units within a buffer)
  int offA[4], offB[4];
  {
    const int c16r = lane >> 4;                 // 0..3 (BK=32: one kk)
    #pragma unroll
    for (int i = 0; i < 4; ++i) {
      const int ra = wm * 64 + i * 16 + frow;
      const int rb = wn * 64 + i * 16 + frow;
      offA[i] = ra * (BK * 2) + ((c16r ^ ((ra >> 1) & MASK)) * 16);
      offB[i] = rb * (BK * 2) + ((c16r ^ ((rb >> 1) & MASK)) * 16);
    }
  }

  auto bufA = [&](int b) { return smem + b * 2 * BUFB; };
  auto bufB = [&](int b) { return smem + b * 2 * BUFB + BUFB; };

  auto stage = [&](int b, int kt) {
    const int kb = kt * (BK * 2);
    #pragma unroll
    for (int L = 0; L < NISS; ++L) {
      const int seg = L * 256 + wid * 64 + lane;
      const int row = seg / SEGR, c16 = seg & MASK;
      const int c16s = c16 ^ ((row >> 1) & MASK);          // pre-swizzled source
      const size_t go = (size_t)row * (KA * 2) + kb + c16s * 16;
      GLDS16(gA + go, bufA(b) + seg * 16);
      GLDS16(gB + go, bufB(b) + seg * 16);
    }
  };

  f4_t acc[4][4] = {};

  // prologue: tiles 0,1,2 in flight; wait tile 0 (8 loads may remain)
  stage(0, 0);
  stage(1, 1);
  stage(2, 2);
  VMW8;
  __builtin_amdgcn_s_barrier();

  #pragma unroll
  for (int t = 0; t < NKT; ++t) {
    const int cur = t % 3;
    bf8_t af[4], bfv[4];
    #pragma unroll
    for (int i = 0; i < 4; ++i) {
      af[i]  = *(const bf8_t*)(bufA(cur) + offA[i]);
      bfv[i] = *(const bf8_t*)(bufB(cur) + offB[i]);
    }
    if (t < NKT - 1) {
      LKW0;                               // own frag reads done (regs hold tile t)
      __builtin_amdgcn_s_barrier();       // all waves done reading buf[cur]
      SBAR0;                              // pin: no motion across the fence
      if (t + 3 < NKT) stage(cur, t + 3); // overwrite freed buf; stays in flight
    } else {
      LKW0;
      SBAR0;
    }
    __builtin_amdgcn_s_setprio(1);
    #pragma unroll
    for (int mi = 0; mi < 4; ++mi)
      #pragma unroll
      for (int ni = 0; ni < 4; ++ni)
        acc[mi][ni] = __builtin_amdgcn_mfma_f32_16x16x32_bf16(bfv[ni], af[mi], acc[mi][ni], 0, 0, 0);
    __builtin_amdgcn_s_setprio(0);
    if (t < NKT - 1) {
      if (t + 3 < NKT)      { VMW8; }     // tiles t+2,t+3 stay in flight
      else if (t + 2 < NKT) { VMW4; }     // only t+2 in flight
      else                  { VMW0; }     // last prefetch: full drain
      __builtin_amdgcn_s_barrier();
    }
  }

  const int cq = (lane >> 4) * 4;
  if constexpr (!FUSE) {
    #pragma unroll
    for (int mi = 0; mi < 4; ++mi) {
      const int r = row0 + wm * 64 + mi * 16 + frow;
      unsigned short* crow = C + (size_t)r * KD;
      #pragma unroll
      for (int ni = 0; ni < 4; ++ni) {
        const int c = n0 + wn * 64 + ni * 16 + cq;
        if (c < KD) {  // wave-uniform per fragment
          f4_t v = acc[mi][ni];
          const f4_t bb = *(const f4_t*)(bias + c);
          float v0 = fmaxf(v[0] + bb[0], 0.f);
          float v1 = fmaxf(v[1] + bb[1], 0.f);
          float v2 = fmaxf(v[2] + bb[2], 0.f);
          float v3 = fmaxf(v[3] + bb[3], 0.f);
          uint2 pk;
          pk.x = (unsigned int)f2bf(v0) | ((unsigned int)f2bf(v1) << 16);
          pk.y = (unsigned int)f2bf(v2) | ((unsigned int)f2bf(v3) << 16);
          *(uint2*)(crow + c) = pk;
        }
      }
    }
  } else {
    // ---- fused layer-3 epilogue ----
    // relu tile -> LDS [128][128] bf16 (32 KB within smem), byte ^= (row&7)<<4.
    unsigned short* sT = (unsigned short*)smem;
    __syncthreads();   // all waves past their last frag reads before overwrite
    #pragma unroll
    for (int mi = 0; mi < 4; ++mi) {
      const int lr = wm * 64 + mi * 16 + frow;
      #pragma unroll
      for (int ni = 0; ni < 4; ++ni) {
        const int lc = wn * 64 + ni * 16 + cq;
        f4_t v = acc[mi][ni];
        const f4_t bb = *(const f4_t*)(bias + (n0 + lc));   // bias is NPW-wide
        float v0 = fmaxf(v[0] + bb[0], 0.f);
        float v1 = fmaxf(v[1] + bb[1], 0.f);
        float v2 = fmaxf(v[2] + bb[2], 0.f);
        float v3 = fmaxf(v[3] + bb[3], 0.f);
        uint2 pk;
        pk.x = (unsigned int)f2bf(v0) | ((unsigned int)f2bf(v1) << 16);
        pk.y = (unsigned int)f2bf(v2) | ((unsigned int)f2bf(v3) << 16);
        const int bo = (lr * 256 + lc * 2) ^ ((lr & 7) << 4);
        *(uint2*)((char*)sT + bo) = pk;
      }
    }
    __syncthreads();
    // mini-GEMM: out_partial[128][16] = tile[128][128] @ Wt3[n0:n0+128]^T
    const int fk = (lane >> 4) * 8;
    f4_t acc2[2] = {};
    #pragma unroll
    for (int kk2 = 0; kk2 < 4; ++kk2) {
      const bf8_t bw = *(const bf8_t*)(W3t + (size_t)frow * KW3 + n0 + kk2 * 32 + fk);
      #pragma unroll
      for (int mi2 = 0; mi2 < 2; ++mi2) {
        const int lr2 = wid * 32 + mi2 * 16 + frow;
        const int bo = (lr2 * 256 + (kk2 * 32 + fk) * 2) ^ ((lr2 & 7) << 4);
        const bf8_t av = *(const bf8_t*)((char*)sT + bo);
        acc2[mi2] = __builtin_amdgcn_mfma_f32_16x16x32_bf16(bw, av, acc2[mi2], 0, 0, 0);
      }
    }
    // atomic accumulate into out (pre-initialized to b3)
    #pragma unroll
    for (int mi2 = 0; mi2 < 2; ++mi2) {
      const int r2 = row0 + wid * 32 + mi2 * 16 + frow;
      if (r2 < NROWS && cq < 12) {
        float* orow = out3 + (size_t)r2 * 12 + cq;
        atomicAdd(&orow[0], acc2[mi2][0]);
        atomicAdd(&orow[1], acc2[mi2][1]);
        atomicAdd(&orow[2], acc2[mi2][2]);
        atomicAdd(&orow[3], acc2[mi2][3]);
      }
    }
  }
}

// ---------------- host ----------------
extern "C" void kernel_launch(void* const* d_in, const int* in_sizes, int n_in,
                              void* d_out, int out_size, void* d_ws, size_t ws_size,
                              hipStream_t stream) {
  const float* mixer    = (const float*)d_in[0];
  const float* features = (const float*)d_in[1];
  const int*   sg_batch = (const int*)d_in[2];
  const int*   sg_map   = (const int*)d_in[3];
  const float* W0 = (const float*)d_in[4];  const float* b0 = (const float*)d_in[5];
  const float* W1 = (const float*)d_in[6];  const float* b1 = (const float*)d_in[7];
  const float* W2 = (const float*)d_in[8];  const float* b2 = (const float*)d_in[9];
  const float* W3 = (const float*)d_in[10]; const float* b3 = (const float*)d_in[11];
  float* out = (float*)d_out;

  char* wsp = (char*)d_ws;
  auto alloc = [&](size_t bytes) { char* p = wsp; wsp += (bytes + 255) & ~(size_t)255; return p; };
  unsigned short* h0  = (unsigned short*)alloc((size_t)MPAD * KD * 2);   // 66.7 MB
  unsigned short* h1  = (unsigned short*)alloc((size_t)MPAD * KD * 2);   // 66.7 MB
  unsigned short* Wt1 = (unsigned short*)alloc((size_t)NPW * KD * 2);
  unsigned short* Wt2 = (unsigned short*)alloc((size_t)NPW * KD * 2);
  unsigned short* Wt3 = (unsigned short*)alloc((size_t)16 * KW3 * 2);
  unsigned short* WTB = (unsigned short*)alloc((size_t)NPW * KA0 * 2);
  float* bp0   = (float*)alloc(NPW * 4);
  float* bp1   = (float*)alloc(NPW * 4);
  float* bp2   = (float*)alloc(NPW * 4);
  float* fW0   = (float*)alloc((size_t)128 * KD * 4);
  int* counts  = (int*)alloc(NSEG * 4);
  // Cff (20.5 MB f32) and Abuf (12.8 MB bf16) alias h1's space: both are dead
  // before the first write to h1 (layer-1 GEMM output).
  float* Cff = (float*)h1;
  unsigned short* Abuf = (unsigned short*)((char*)h1 + (((size_t)NROWS * 128 * 4 + 255) & ~(size_t)255));

  // init: counts=0, Cff=0 (memset), out=b3 (small kernel)
  hipMemsetAsync(counts, 0, NSEG * 4, stream);
  hipMemsetAsync(Cff, 0, (size_t)NROWS * 128 * 4, stream);
  k_outinit<<<(NROWS * 12 + 255) / 256, 256, 0, stream>>>(out, b3);

  // fused count + Cf scatter
  k_edges<<<(EN + 255) / 256, 256, 0, stream>>>(sg_map, sg_batch, counts, Cff);

  // weight prep
  k_flatW0<<<dim3(13, 16), 256, 0, stream>>>(mixer, W0, fW0);
  {
    const int total = 2 * (NPW * KD) + 16 * KW3 + 3 * NPW + NPW * KA0;
    k_prep<<<(total + 255) / 256, 256, 0, stream>>>(W0, fW0, W1, W2, W3, b0, b1, b2,
                                                    Wt1, Wt2, Wt3, bp0, bp1, bp2, WTB);
  }

  // layer-0 operand A = [features | Cf | 0]
  k_buildA<<<(MPAD * KA0 + 255) / 256, 256, 0, stream>>>(features, counts, Cff, Abuf);

  // layer 0 as GEMM (K=160) -> h0
  gemm_relu<KA0, false><<<(MPAD / 128) * NT, 256, 0, stream>>>(Abuf, WTB, bp0, h0, nullptr, nullptr);

  // layer 1 (K=832) -> h1
  gemm_relu<KD, false><<<(MPAD / 128) * NT, 256, 0, stream>>>(h0, Wt1, bp1, h1, nullptr, nullptr);

  // layer 2 + fused layer 3 (K=832): atomic out += tile @ Wt3
  gemm_relu<KD, true><<<(MPAD / 128) * NT, 256, 0, stream>>>(h1, Wt2, bp2, nullptr, Wt3, out);
}